// Round 1
// 319.337 us; speedup vs baseline: 1.0561x; 1.0561x over previous
//
#include <hip/hip_runtime.h>
#include <math.h>

#define HID 2048
#define NH 32
#define NKV 8
#define HD 64
#define BB 2
#define SS 2048
#define MTOT (BB * SS) // 4096

typedef __bf16 bf16;
typedef __bf16 bf16x8 __attribute__((ext_vector_type(8)));
typedef __bf16 bf16x4 __attribute__((ext_vector_type(4)));
typedef float f32x4 __attribute__((ext_vector_type(4)));

#define MFMA16(a, b, c) __builtin_amdgcn_mfma_f32_16x16x32_bf16((a), (b), (c), 0, 0, 0)

__device__ __forceinline__ void load_lds16(const void* g, void* l) {
  __builtin_amdgcn_global_load_lds((const __attribute__((address_space(1))) void*)g,
                                   (__attribute__((address_space(3))) void*)l, 16, 0, 0);
}

#define FENCE() asm volatile("" ::: "memory")
#define BARX() do { FENCE(); __builtin_amdgcn_s_barrier(); FENCE(); } while (0)
// Tile-top sync: counted vmcnt (never 0 in main loop) + lgkmcnt(0) so this
// wave's ds_reads have COMPLETED before it enters the barrier (orders them
// against other waves' post-barrier global_load_lds writebacks), then barrier.
#define SYNC_VM(N) do { FENCE(); \
  asm volatile("s_waitcnt vmcnt(" #N ") lgkmcnt(0)" ::: "memory"); \
  __builtin_amdgcn_s_barrier(); FENCE(); } while (0)

// ---------------- fused fp32 -> bf16 convert (all 5 tensors, one launch) ----------------
__global__ void cvt_all(const float* __restrict__ hs, const float* __restrict__ Wq,
                        const float* __restrict__ Wk, const float* __restrict__ Wv,
                        const float* __restrict__ Wo,
                        bf16* __restrict__ A_b, bf16* __restrict__ Wq_b,
                        bf16* __restrict__ Wk_b, bf16* __restrict__ Wv_b,
                        bf16* __restrict__ Wo_b) {
  int bid = blockIdx.x;
  const float* src;
  bf16* dst;
  if (bid < 8192)       { src = hs; dst = A_b; }
  else if (bid < 12288) { src = Wq; dst = Wq_b; bid -= 8192; }
  else if (bid < 13312) { src = Wk; dst = Wk_b; bid -= 12288; }
  else if (bid < 14336) { src = Wv; dst = Wv_b; bid -= 13312; }
  else                  { src = Wo; dst = Wo_b; bid -= 14336; }
  int i = (bid * 256 + threadIdx.x) * 4;
  float4 v = *(const float4*)(src + i);
  bf16x4 o;
  o[0] = (bf16)v.x; o[1] = (bf16)v.y; o[2] = (bf16)v.z; o[3] = (bf16)v.w;
  *(bf16x4*)(dst + i) = o;
}

// ---------------- pipelined GEMM core: C = A * W^T, K = 2048 ----------------
// 512 threads = 8 waves (2M x 4N); wave output tile = (MR*16) x 64.
// BM = MR*32 (256 or 128), BN = 256 fixed, BK = 32 per K-tile.
// THREE LDS buffers, rotating: while computing tile kt (buf kt%3), stage tile
// kt+2 into buf (kt+2)%3. One s_waitcnt vmcnt(NLOAD) per K-tile -- loads stay
// in flight across barriers (T3+T4); never drained to 0 in the main loop.
// LDS swizzle (T2): logical row R (BK=32 bf16 = 64B = 4 chunks of 16B) stored
// at byte p*128 + cg*16 with p = R>>1, cg = (((R&1)<<2)|c) ^ (p&7).
// A 16-lane column read then touches each of the 8 bank-line slots exactly
// twice (2-way aliasing = free, m136). Applied on the GLOBAL source address
// for staging (global_load_lds dest must stay linear, m104/m173) and on the
// ds_read address.
template <int MR>
__device__ __forceinline__ void gemm_core(const char* Agc, const char* Bgc,
                                          char* lds, f32x4 (&acc)[MR][4]) {
  constexpr int ABYTES = MR * 32 * 64;        // A tile bytes (BM x 32 bf16)
  constexpr int BUFB = ABYTES + 16384;        // + B tile (256 x 32 bf16)
  constexpr int NT = HID / 32;                // 64 K-tiles

  const int tid = threadIdx.x;
  const int w = tid >> 6, lane = tid & 63;
  const int l16 = lane & 15, quad = lane >> 4;
  const int wr = w >> 2, wc = w & 3;
  const int wb = w * 1024;

  // staging: thread t owns LDS 16B-slot t -> (p = t>>3, cg = t&7); invert the
  // swizzle to get the global (row, chunk) it must fetch.
  const int cu = (tid & 7) ^ ((tid >> 3) & 7);
  const int srcR0 = 2 * (tid >> 3) + (cu >> 2);   // 0..127 (+128 for instr 1)
  const int srcC = (cu & 3) * 16;
  const char* gA = Agc + (size_t)srcR0 * (HID * 2) + srcC;
  const char* gB = Bgc + (size_t)srcR0 * (HID * 2) + srcC;

  // ds_read base offsets: frag (mi) at aoff + mi*1024 (16 rows = 8 pairs = 1KB)
  const int acg16 = ((((l16 & 1) << 2) | quad) ^ ((l16 >> 1) & 7)) * 16;
  const int aoff = (wr * (MR * 8) + (l16 >> 1)) * 128 + acg16;
  const int boff = (wc * 32 + (l16 >> 1)) * 128 + acg16;

  // prologue: stage tiles 0 and 1 (NLOAD per tile per wave; NLOAD = MR/4 + 2)
#pragma unroll
  for (int t0 = 0; t0 < 2; ++t0) {
    char* lb = lds + t0 * BUFB;
    load_lds16(gA + t0 * 64, lb + wb);
    if constexpr (MR == 8)
      load_lds16(gA + (size_t)128 * (HID * 2) + t0 * 64, lb + 8192 + wb);
    load_lds16(gB + t0 * 64, lb + ABYTES + wb);
    load_lds16(gB + (size_t)128 * (HID * 2) + t0 * 64, lb + ABYTES + 8192 + wb);
  }

  char* cur = lds;
  char* stg = lds + 2 * BUFB;
  for (int kt = 0; kt < NT; ++kt) {
    // wait until only tile kt+1's loads remain outstanding -> tile kt landed.
    if constexpr (MR == 8) SYNC_VM(4); else SYNC_VM(3);
    // clamp: tail iterations re-stage tile NT-1 into a buffer never read.
    const int ks = (kt + 2 <= NT - 1) ? (kt + 2) * 64 : (NT - 1) * 64;
    const char* Ac = cur;
    const char* Bc = cur + ABYTES;

    // ---- phase 0: stage half of tile kt+2, read B + low-half A, 16 MFMA ----
    load_lds16(gA + ks, stg + wb);
    load_lds16(gB + ks, stg + ABYTES + wb);
    bf16x8 bfr[4];
#pragma unroll
    for (int ni = 0; ni < 4; ++ni)
      bfr[ni] = *(const bf16x8*)(Bc + boff + ni * 1024);
    bf16x8 af[MR / 2];
#pragma unroll
    for (int mi = 0; mi < MR / 2; ++mi)
      af[mi] = *(const bf16x8*)(Ac + aoff + mi * 1024);
    __builtin_amdgcn_s_setprio(1);
#pragma unroll
    for (int mi = 0; mi < MR / 2; ++mi)
#pragma unroll
      for (int ni = 0; ni < 4; ++ni)
        acc[mi][ni] = MFMA16(af[mi], bfr[ni], acc[mi][ni]);
    __builtin_amdgcn_s_setprio(0);
    BARX();

    // ---- phase 1: stage rest of tile kt+2, read high-half A, 16 MFMA ----
    if constexpr (MR == 8)
      load_lds16(gA + (size_t)128 * (HID * 2) + ks, stg + 8192 + wb);
    load_lds16(gB + (size_t)128 * (HID * 2) + ks, stg + ABYTES + 8192 + wb);
#pragma unroll
    for (int mi = 0; mi < MR / 2; ++mi)
      af[mi] = *(const bf16x8*)(Ac + aoff + (MR / 2 + mi) * 1024);
    __builtin_amdgcn_s_setprio(1);
#pragma unroll
    for (int mi = 0; mi < MR / 2; ++mi)
#pragma unroll
      for (int ni = 0; ni < 4; ++ni)
        acc[MR / 2 + mi][ni] = MFMA16(af[mi], bfr[ni], acc[MR / 2 + mi][ni]);
    __builtin_amdgcn_s_setprio(0);

    cur = (cur == lds + 2 * BUFB) ? lds : cur + BUFB;
    stg = (stg == lds + 2 * BUFB) ? lds : stg + BUFB;
  }
  // drain stray (clamped) stage loads before the workgroup can exit.
  asm volatile("s_waitcnt vmcnt(0)" ::: "memory");
}

// ---------------- fused QKV projection + RoPE epilogue ----------------
#define QSCALE 0.1803368801f
#define L2B 0.4152410118f  // log2(10000)/32
__global__ __launch_bounds__(512, 2) void gemm_qkv(const bf16* __restrict__ A,
                                                   const bf16* __restrict__ Wq,
                                                   const bf16* __restrict__ Wk,
                                                   const bf16* __restrict__ Wv,
                                                   bf16* __restrict__ Qb,
                                                   bf16* __restrict__ Kb,
                                                   bf16* __restrict__ Vt) {
  __shared__ __align__(16) char lds[3 * (256 * 64 + 16384)];  // 96 KB
  const int tileM = blockIdx.x * 256;
  const int n0 = blockIdx.y * 256;
  const bf16* Wp;
  int mode;
  if (n0 < HID) { Wp = Wq + (size_t)n0 * HID; mode = 0; }
  else if (n0 < HID + 512) { Wp = Wk + (size_t)(n0 - HID) * HID; mode = 1; }
  else { Wp = Wv + (size_t)(n0 - HID - 512) * HID; mode = 2; }

  f32x4 acc[8][4];
#pragma unroll
  for (int i = 0; i < 8; ++i)
#pragma unroll
    for (int j = 0; j < 4; ++j) acc[i][j] = (f32x4){0.f, 0.f, 0.f, 0.f};

  gemm_core<8>((const char*)(A + (size_t)tileM * HID), (const char*)Wp, lds, acc);

  const int tid = threadIdx.x;
  const int w = tid >> 6, lane = tid & 63;
  const int l16 = lane & 15, quad = lane >> 4;
  const int wr = w >> 2, wc = w & 3;
  const int mbase = tileM + wr * 128;
  const int cb = n0 + wc * 64;  // 64-aligned -> wave col span = one head

  if (mode == 2) {
    // V: transposed layout [b,kvh,d,s]
#pragma unroll
    for (int mi = 0; mi < 8; ++mi)
#pragma unroll
      for (int ni = 0; ni < 4; ++ni)
#pragma unroll
        for (int r = 0; r < 4; ++r) {
          int grow = mbase + mi * 16 + quad * 4 + r;
          int b = grow >> 11, spos = grow & (SS - 1);
          int nv = cb + ni * 16 + l16 - (HID + 512);
          Vt[(((size_t)(b * NKV + (nv >> 6))) * HD + (nv & 63)) * SS + spos] =
              (bf16)acc[mi][ni][r];
        }
  } else {
    // Q or K: RoPE in fp32 regs. In-head col of ni is i = ni*16 + l16, so
    // pairs are (ni=0,ni=2) at freq idx l16 and (ni=1,ni=3) at l16+16.
    const float inv0 = __builtin_amdgcn_exp2f(-(float)l16 * L2B);
    const float inv1 = __builtin_amdgcn_exp2f(-(float)(l16 + 16) * L2B);
#pragma unroll
    for (int mi = 0; mi < 8; ++mi) {
#pragma unroll
      for (int r = 0; r < 4; ++r) {
        int grow = mbase + mi * 16 + quad * 4 + r;
        int b = grow >> 11, spos = grow & (SS - 1);
        float sn0, cs0, sn1, cs1;
        sincosf((float)spos * inv0, &sn0, &cs0);
        sincosf((float)spos * inv1, &sn1, &cs1);
        float a0 = acc[mi][0][r], a1 = acc[mi][1][r];
        float a2 = acc[mi][2][r], a3 = acc[mi][3][r];
        float o0 = a0 * cs0 - a2 * sn0;
        float o2 = a2 * cs0 + a0 * sn0;
        float o1 = a1 * cs1 - a3 * sn1;
        float o3 = a3 * cs1 + a1 * sn1;
        if (mode == 0) {
          bf16* qp = Qb + (size_t)grow * HID + cb + l16;
          qp[0]  = (bf16)(o0 * QSCALE);
          qp[16] = (bf16)(o1 * QSCALE);
          qp[32] = (bf16)(o2 * QSCALE);
          qp[48] = (bf16)(o3 * QSCALE);
        } else {
          int kvh = (cb - HID) >> 6;
          bf16* kp = Kb + ((size_t)(b * NKV + kvh) * SS + spos) * HD + l16;
          kp[0]  = (bf16)o0;
          kp[16] = (bf16)o1;
          kp[32] = (bf16)o2;
          kp[48] = (bf16)o3;
        }
      }
    }
  }
}

// ---------------- output projection (BM=128 -> grid 32x8 = 256 blocks) ----------------
__global__ __launch_bounds__(512, 2) void gemm_out(const bf16* __restrict__ A,
                                                   const bf16* __restrict__ Wo,
                                                   float* __restrict__ out) {
  __shared__ __align__(16) char lds[3 * (128 * 64 + 16384)];  // 72 KB
  const int tileM = blockIdx.x * 128;
  const int n0 = blockIdx.y * 256;
  f32x4 acc[4][4];
#pragma unroll
  for (int i = 0; i < 4; ++i)
#pragma unroll
    for (int j = 0; j < 4; ++j) acc[i][j] = (f32x4){0.f, 0.f, 0.f, 0.f};

  gemm_core<4>((const char*)(A + (size_t)tileM * HID),
               (const char*)(Wo + (size_t)n0 * HID), lds, acc);

  const int tid = threadIdx.x;
  const int w = tid >> 6, lane = tid & 63;
  const int l16 = lane & 15, quad = lane >> 4;
  const int wr = w >> 2, wc = w & 3;
#pragma unroll
  for (int mi = 0; mi < 4; ++mi)
#pragma unroll
    for (int ni = 0; ni < 4; ++ni)
#pragma unroll
      for (int r = 0; r < 4; ++r) {
        int grow = tileM + wr * 64 + mi * 16 + quad * 4 + r;
        int gcol = n0 + wc * 64 + ni * 16 + l16;
        out[(size_t)grow * HID + gcol] = acc[mi][ni][r];
      }
}

// ---------------- flash attention v5: block-cooperative LDS staging ----------------
#define PSTR 72
__global__ __launch_bounds__(256, 3) void attn(const bf16* __restrict__ Qb,
                                               const bf16* __restrict__ Kb,
                                               const bf16* __restrict__ Vt,
                                               bf16* __restrict__ Ctx) {
  __shared__ bf16 Ktile[2][64 * 64];
  __shared__ bf16 Vtile[2][64 * 64];
  __shared__ bf16 Pbuf[4][16 * PSTR];
  const int tid = threadIdx.x;
  const int w = tid >> 6, lane = tid & 63;
  const int l16 = lane & 15, quad = lane >> 4;
  const int bh = blockIdx.y, b = bh >> 5, h = bh & 31, kvh = h >> 2;
  bf16* Pw = &Pbuf[w][0];
  const char* Kslice = (const char*)(Kb + ((size_t)(b * NKV + kvh)) * SS * HD);
  const char* Vslice = (const char*)(Vt + ((size_t)(b * NKV + kvh)) * HD * SS);
  const int qrel = w * 16 + l16;

  const int srow = (lane >> 3) & 7;
  const int pchunk = ((lane & 7) ^ srow) << 4;
  const int so = ((quad ^ (l16 & 7)) << 4);
  const int so2 = so ^ 64;

  const int qtA = (int)blockIdx.x;

  int cur = 0;
  {
#pragma unroll
    for (int i = 0; i < 2; ++i) {
      const int r = w * 16 + i * 8 + srow;
      load_lds16(Kslice + (size_t)r * 128 + pchunk,
                 (char*)Ktile[0] + (w * 16 + i * 8) * 128);
      load_lds16(Vslice + (size_t)r * 4096 + pchunk,
                 (char*)Vtile[0] + (w * 16 + i * 8) * 128);
    }
  }

  for (int t = 0; t < 2; ++t) {
    const int qt = t ? (31 - qtA) : qtA;
    const int q = qt * 64 + qrel;

    const bf16* Qp = Qb + ((size_t)(b * SS + q)) * HID + h * HD + quad * 8;
    bf16x8 qb0 = *(const bf16x8*)Qp;
    bf16x8 qb1 = *(const bf16x8*)(Qp + 32);

    float l = 0.f;
    f32x4 oacc[4];
#pragma unroll
    for (int d = 0; d < 4; ++d) oacc[d] = (f32x4){0.f, 0.f, 0.f, 0.f};

    for (int kt = 0; kt <= qt; ++kt) {
      __syncthreads();

      const bool have_next = (kt < qt) || (t == 0);
      if (have_next) {
        const int nkb = (kt < qt) ? (kt + 1) * 64 : 0;
        const int nb = cur ^ 1;
#pragma unroll
        for (int i = 0; i < 2; ++i) {
          const int r = w * 16 + i * 8 + srow;
          load_lds16(Kslice + (size_t)(nkb + r) * 128 + pchunk,
                     (char*)Ktile[nb] + (w * 16 + i * 8) * 128);
          load_lds16(Vslice + (size_t)r * 4096 + (size_t)nkb * 2 + pchunk,
                     (char*)Vtile[nb] + (w * 16 + i * 8) * 128);
        }
      }

      const char* Kc = (const char*)Ktile[cur] + l16 * 128;
      const char* Vc = (const char*)Vtile[cur] + l16 * 128;
      const bool diag = (kt == qt);

#pragma unroll
      for (int nt = 0; nt < 4; ++nt) {
        bf16x8 kf0 = *(const bf16x8*)(Kc + nt * 2048 + so);
        bf16x8 kf1 = *(const bf16x8*)(Kc + nt * 2048 + so2);
        f32x4 s = {0.f, 0.f, 0.f, 0.f};
        s = MFMA16(kf0, qb0, s);
        s = MFMA16(kf1, qb1, s);
        bf16x4 pk;
        if (diag) {
          const int krel = nt * 16 + quad * 4;
#pragma unroll
          for (int r = 0; r < 4; ++r) {
            float p = (krel + r > qrel) ? 0.f : __builtin_amdgcn_exp2f(s[r]);
            l += p;
            pk[r] = (bf16)p;
          }
        } else {
#pragma unroll
          for (int r = 0; r < 4; ++r) {
            float p = __builtin_amdgcn_exp2f(s[r]);
            l += p;
            pk[r] = (bf16)p;
          }
        }
        *(bf16x4*)&Pw[l16 * PSTR + nt * 16 + quad * 4] = pk;
      }

      bf16x8 p0 = *(const bf16x8*)&Pw[l16 * PSTR + quad * 8];
      bf16x8 p1 = *(const bf16x8*)&Pw[l16 * PSTR + 32 + quad * 8];
#pragma unroll
      for (int dn = 0; dn < 4; ++dn) {
        bf16x8 v0 = *(const bf16x8*)(Vc + dn * 2048 + so);
        bf16x8 v1 = *(const bf16x8*)(Vc + dn * 2048 + so2);
        oacc[dn] = MFMA16(v0, p0, oacc[dn]);
        oacc[dn] = MFMA16(v1, p1, oacc[dn]);
      }
      cur ^= 1;
    }

    l += __shfl_xor(l, 16);
    l += __shfl_xor(l, 32);
    const float inv = 1.0f / l;
    bf16* Cp = Ctx + ((size_t)(b * SS + q)) * HID + h * HD + quad * 4;
#pragma unroll
    for (int dn = 0; dn < 4; ++dn) {
      bf16x4 ov;
#pragma unroll
      for (int r = 0; r < 4; ++r) ov[r] = (bf16)(oacc[dn][r] * inv);
      *(bf16x4*)(Cp + dn * 16) = ov;
    }
  }
}

// ---------------- launch ----------------
extern "C" void kernel_launch(void* const* d_in, const int* in_sizes, int n_in,
                              void* d_out, int out_size, void* d_ws, size_t ws_size,
                              hipStream_t stream) {
  const float* hs = (const float*)d_in[0];
  const float* Wq = (const float*)d_in[2];
  const float* Wk = (const float*)d_in[3];
  const float* Wv = (const float*)d_in[4];
  const float* Wo = (const float*)d_in[5];

  char* ws = (char*)d_ws;
  bf16* A_b  = (bf16*)(ws);              // 16 MB ; reused as Ctx after QKV gemm
  bf16* Wq_b = (bf16*)(ws + 16777216);   // 8 MB
  bf16* Wk_b = (bf16*)(ws + 25165824);   // 2 MB
  bf16* Wv_b = (bf16*)(ws + 27262976);   // 2 MB
  bf16* Wo_b = (bf16*)(ws + 29360128);   // 8 MB
  bf16* Qb   = (bf16*)(ws + 37748736);   // 16 MB
  bf16* Kb   = (bf16*)(ws + 54525952);   // 4 MB
  bf16* Vt   = (bf16*)(ws + 58720256);   // 4 MB  (end: 62914560)
  bf16* Ctx  = A_b;

  cvt_all<<<18432, 256, 0, stream>>>(hs, Wq, Wk, Wv, Wo, A_b, Wq_b, Wk_b, Wv_b, Wo_b);
  gemm_qkv<<<dim3(MTOT / 256, 12), 512, 0, stream>>>(A_b, Wq_b, Wk_b, Wv_b, Qb, Kb, Vt);
  attn<<<dim3(16, BB * NH), 256, 0, stream>>>(Qb, Kb, Vt, Ctx);
  gemm_out<<<dim3(MTOT / 128, HID / 256), 512, 0, stream>>>(Ctx, Wo_b, (float*)d_out);
}

// Round 2
// 305.854 us; speedup vs baseline: 1.1027x; 1.0441x over previous
//
#include <hip/hip_runtime.h>
#include <math.h>

#define HID 2048
#define NH 32
#define NKV 8
#define HD 64
#define BB 2
#define SS 2048
#define MTOT (BB * SS) // 4096

typedef __bf16 bf16;
typedef __bf16 bf16x8 __attribute__((ext_vector_type(8)));
typedef __bf16 bf16x4 __attribute__((ext_vector_type(4)));
typedef float f32x4 __attribute__((ext_vector_type(4)));

#define MFMA16(a, b, c) __builtin_amdgcn_mfma_f32_16x16x32_bf16((a), (b), (c), 0, 0, 0)

__device__ __forceinline__ void load_lds16(const void* g, void* l) {
  __builtin_amdgcn_global_load_lds((const __attribute__((address_space(1))) void*)g,
                                   (__attribute__((address_space(3))) void*)l, 16, 0, 0);
}

#define FENCE() asm volatile("" ::: "memory")
// Tile-top sync: counted vmcnt (never 0 in main loop) + lgkmcnt(0) so this
// wave's ds_reads have COMPLETED before it enters the barrier (orders them
// against other waves' post-barrier global_load_lds writebacks), then barrier.
#define SYNC_VM(N) do { FENCE(); \
  asm volatile("s_waitcnt vmcnt(" #N ") lgkmcnt(0)" ::: "memory"); \
  __builtin_amdgcn_s_barrier(); FENCE(); } while (0)

// ---------------- fused fp32 -> bf16 convert (all 5 tensors, one launch) ----------------
__global__ void cvt_all(const float* __restrict__ hs, const float* __restrict__ Wq,
                        const float* __restrict__ Wk, const float* __restrict__ Wv,
                        const float* __restrict__ Wo,
                        bf16* __restrict__ A_b, bf16* __restrict__ Wq_b,
                        bf16* __restrict__ Wk_b, bf16* __restrict__ Wv_b,
                        bf16* __restrict__ Wo_b) {
  int bid = blockIdx.x;
  const float* src;
  bf16* dst;
  if (bid < 8192)       { src = hs; dst = A_b; }
  else if (bid < 12288) { src = Wq; dst = Wq_b; bid -= 8192; }
  else if (bid < 13312) { src = Wk; dst = Wk_b; bid -= 12288; }
  else if (bid < 14336) { src = Wv; dst = Wv_b; bid -= 13312; }
  else                  { src = Wo; dst = Wo_b; bid -= 14336; }
  int i = (bid * 256 + threadIdx.x) * 4;
  float4 v = *(const float4*)(src + i);
  bf16x4 o;
  o[0] = (bf16)v.x; o[1] = (bf16)v.y; o[2] = (bf16)v.z; o[3] = (bf16)v.w;
  *(bf16x4*)(dst + i) = o;
}

// ---------------- pipelined GEMM core: C = A * W^T, K = 2048 ----------------
// 256 threads = 4 waves (2M x 2N); wave output tile = 64x64; BM = BN = 128,
// BK = 32 per K-tile. 48 KB LDS -> 3 workgroups/CU (12 waves) so cross-block
// overlap hides barrier stalls (m114). THREE rotating LDS buffers: while
// computing tile kt (buf kt%3), stage tile kt+2 into buf (kt+2)%3. One
// s_waitcnt vmcnt(4) + ONE barrier per K-tile -- loads stay in flight across
// the barrier (T3+T4 counted-vmcnt); never drained to 0 in the main loop.
// LDS swizzle (T2, verified round 1: conflicts -> 0): logical row R (64 B = 4
// chunks of 16B) stored at byte p*128 + cg*16, p = R>>1, cg = (((R&1)<<2)|c) ^
// (p&7). Inverse applied on the GLOBAL source address for staging
// (global_load_lds dest must stay linear), same XOR on the ds_read address.
__device__ __forceinline__ void gemm_core(const char* Agc, const char* Bgc,
                                          char* lds, f32x4 (&acc)[4][4]) {
  constexpr int ABYTES = 8192;      // A tile bytes (128 x 32 bf16)
  constexpr int BUFB = 16384;       // + B tile (128 x 32 bf16)
  constexpr int NT = HID / 32;      // 64 K-tiles

  const int tid = threadIdx.x;
  const int w = tid >> 6, lane = tid & 63;
  const int l16 = lane & 15, quad = lane >> 4;
  const int wr = w >> 1, wc = w & 1;
  const int wb = w * 1024;

  // staging: thread t owns LDS 16B-slot t of a 4 KB half-tile (64 rows);
  // invert the swizzle to get the global (row, chunk) it must fetch.
  const int cu = (tid & 7) ^ ((tid >> 3) & 7);
  const int srcR0 = 2 * (tid >> 3) + (cu >> 2);   // 0..63 (+64 for 2nd instr)
  const int srcC = (cu & 3) * 16;
  const char* gA = Agc + (size_t)srcR0 * (HID * 2) + srcC;
  const char* gB = Bgc + (size_t)srcR0 * (HID * 2) + srcC;

  // ds_read offsets: fragment mi/ni at base + idx*1024 (16 rows = 8 pairs)
  const int acg16 = ((((l16 & 1) << 2) | quad) ^ ((l16 >> 1) & 7)) * 16;
  const int aoff = (wr * 32 + (l16 >> 1)) * 128 + acg16;
  const int boff = (wc * 32 + (l16 >> 1)) * 128 + acg16;

  // prologue: stage tiles 0 and 1 (4 loads per tile per wave)
#pragma unroll
  for (int t0 = 0; t0 < 2; ++t0) {
    char* lb = lds + t0 * BUFB;
    load_lds16(gA + t0 * 64, lb + wb);
    load_lds16(gA + (size_t)64 * (HID * 2) + t0 * 64, lb + 4096 + wb);
    load_lds16(gB + t0 * 64, lb + ABYTES + wb);
    load_lds16(gB + (size_t)64 * (HID * 2) + t0 * 64, lb + ABYTES + 4096 + wb);
  }

  char* cur = lds;
  char* stg = lds + 2 * BUFB;
  for (int kt = 0; kt < NT; ++kt) {
    // all but the newest 4 loads (tile kt+1's) complete -> tile kt resident;
    // lgkmcnt(0)+barrier also makes it safe to overwrite buf (kt+2)%3, which
    // every wave finished reading during iteration kt-1.
    SYNC_VM(4);
    // tail clamp: re-stage tile NT-1 into a buffer that is never read.
    const int ks = (kt + 2 < NT) ? (kt + 2) * 64 : (NT - 1) * 64;

    // issue async stage of tile kt+2 (stays in flight across next barrier)
    load_lds16(gA + ks, stg + wb);
    load_lds16(gA + (size_t)64 * (HID * 2) + ks, stg + 4096 + wb);
    load_lds16(gB + ks, stg + ABYTES + wb);
    load_lds16(gB + (size_t)64 * (HID * 2) + ks, stg + ABYTES + 4096 + wb);
    FENCE();  // pin stage-issue before the ds_reads

    bf16x8 af[4], bfr[4];
#pragma unroll
    for (int ni = 0; ni < 4; ++ni)
      bfr[ni] = *(const bf16x8*)(cur + ABYTES + boff + ni * 1024);
#pragma unroll
    for (int mi = 0; mi < 4; ++mi)
      af[mi] = *(const bf16x8*)(cur + aoff + mi * 1024);
    __builtin_amdgcn_s_setprio(1);
#pragma unroll
    for (int mi = 0; mi < 4; ++mi)
#pragma unroll
      for (int ni = 0; ni < 4; ++ni)
        acc[mi][ni] = MFMA16(af[mi], bfr[ni], acc[mi][ni]);
    __builtin_amdgcn_s_setprio(0);

    cur = (cur == lds + 2 * BUFB) ? lds : cur + BUFB;
    stg = (stg == lds + 2 * BUFB) ? lds : stg + BUFB;
  }
  // drain stray (clamped) stage loads before workgroup exit.
  asm volatile("s_waitcnt vmcnt(0)" ::: "memory");
}

// ---------------- fused QKV projection + RoPE epilogue ----------------
#define QSCALE 0.1803368801f
#define L2B 0.4152410118f  // log2(10000)/32
__global__ __launch_bounds__(256, 3) void gemm_qkv(const bf16* __restrict__ A,
                                                   const bf16* __restrict__ Wq,
                                                   const bf16* __restrict__ Wk,
                                                   const bf16* __restrict__ Wv,
                                                   bf16* __restrict__ Qb,
                                                   bf16* __restrict__ Kb,
                                                   bf16* __restrict__ Vt) {
  __shared__ __align__(16) char lds[3 * 16384];  // 48 KB -> 3 WG/CU
  const int tileM = blockIdx.x * 128;
  const int n0 = blockIdx.y * 128;
  const bf16* Wp;
  int mode;
  if (n0 < HID) { Wp = Wq + (size_t)n0 * HID; mode = 0; }
  else if (n0 < HID + 512) { Wp = Wk + (size_t)(n0 - HID) * HID; mode = 1; }
  else { Wp = Wv + (size_t)(n0 - HID - 512) * HID; mode = 2; }

  f32x4 acc[4][4];
#pragma unroll
  for (int i = 0; i < 4; ++i)
#pragma unroll
    for (int j = 0; j < 4; ++j) acc[i][j] = (f32x4){0.f, 0.f, 0.f, 0.f};

  gemm_core((const char*)(A + (size_t)tileM * HID), (const char*)Wp, lds, acc);

  const int tid = threadIdx.x;
  const int w = tid >> 6, lane = tid & 63;
  const int l16 = lane & 15, quad = lane >> 4;
  const int mw = (w >> 1) * 64, nw = (w & 1) * 64;  // nw 64-aligned = one head
  const int mbase = tileM + mw;
  const int cb = n0 + nw;

  if (mode == 2) {
    // V: transposed layout [b,kvh,d,s]
#pragma unroll
    for (int mi = 0; mi < 4; ++mi)
#pragma unroll
      for (int ni = 0; ni < 4; ++ni)
#pragma unroll
        for (int r = 0; r < 4; ++r) {
          int grow = mbase + mi * 16 + quad * 4 + r;
          int b = grow >> 11, spos = grow & (SS - 1);
          int nv = cb + ni * 16 + l16 - (HID + 512);
          Vt[(((size_t)(b * NKV + (nv >> 6))) * HD + (nv & 63)) * SS + spos] =
              (bf16)acc[mi][ni][r];
        }
  } else {
    // Q or K: RoPE in fp32 regs. In-head col of ni is i = ni*16 + l16, so
    // pairs are (ni=0,ni=2) at freq idx l16 and (ni=1,ni=3) at l16+16.
    const float inv0 = __builtin_amdgcn_exp2f(-(float)l16 * L2B);
    const float inv1 = __builtin_amdgcn_exp2f(-(float)(l16 + 16) * L2B);
#pragma unroll
    for (int mi = 0; mi < 4; ++mi) {
#pragma unroll
      for (int r = 0; r < 4; ++r) {
        int grow = mbase + mi * 16 + quad * 4 + r;
        int b = grow >> 11, spos = grow & (SS - 1);
        float sn0, cs0, sn1, cs1;
        sincosf((float)spos * inv0, &sn0, &cs0);
        sincosf((float)spos * inv1, &sn1, &cs1);
        float a0 = acc[mi][0][r], a1 = acc[mi][1][r];
        float a2 = acc[mi][2][r], a3 = acc[mi][3][r];
        float o0 = a0 * cs0 - a2 * sn0;
        float o2 = a2 * cs0 + a0 * sn0;
        float o1 = a1 * cs1 - a3 * sn1;
        float o3 = a3 * cs1 + a1 * sn1;
        if (mode == 0) {
          bf16* qp = Qb + (size_t)grow * HID + cb + l16;
          qp[0]  = (bf16)(o0 * QSCALE);
          qp[16] = (bf16)(o1 * QSCALE);
          qp[32] = (bf16)(o2 * QSCALE);
          qp[48] = (bf16)(o3 * QSCALE);
        } else {
          int kvh = (cb - HID) >> 6;
          bf16* kp = Kb + ((size_t)(b * NKV + kvh) * SS + spos) * HD + l16;
          kp[0]  = (bf16)o0;
          kp[16] = (bf16)o1;
          kp[32] = (bf16)o2;
          kp[48] = (bf16)o3;
        }
      }
    }
  }
}

// ---------------- output projection (grid 32x16 = 512 blocks = 2/CU) ----------------
__global__ __launch_bounds__(256, 3) void gemm_out(const bf16* __restrict__ A,
                                                   const bf16* __restrict__ Wo,
                                                   float* __restrict__ out) {
  __shared__ __align__(16) char lds[3 * 16384];
  const int tileM = blockIdx.x * 128;
  const int n0 = blockIdx.y * 128;
  f32x4 acc[4][4];
#pragma unroll
  for (int i = 0; i < 4; ++i)
#pragma unroll
    for (int j = 0; j < 4; ++j) acc[i][j] = (f32x4){0.f, 0.f, 0.f, 0.f};

  gemm_core((const char*)(A + (size_t)tileM * HID),
            (const char*)(Wo + (size_t)n0 * HID), lds, acc);

  const int tid = threadIdx.x;
  const int w = tid >> 6, lane = tid & 63;
  const int l16 = lane & 15, quad = lane >> 4;
  const int mw = (w >> 1) * 64, nw = (w & 1) * 64;
#pragma unroll
  for (int mi = 0; mi < 4; ++mi)
#pragma unroll
    for (int ni = 0; ni < 4; ++ni)
#pragma unroll
      for (int r = 0; r < 4; ++r) {
        int grow = tileM + mw + mi * 16 + quad * 4 + r;
        int gcol = n0 + nw + ni * 16 + l16;
        out[(size_t)grow * HID + gcol] = acc[mi][ni][r];
      }
}

// ---------------- flash attention v5: block-cooperative LDS staging ----------------
#define PSTR 72
__global__ __launch_bounds__(256, 3) void attn(const bf16* __restrict__ Qb,
                                               const bf16* __restrict__ Kb,
                                               const bf16* __restrict__ Vt,
                                               bf16* __restrict__ Ctx) {
  __shared__ bf16 Ktile[2][64 * 64];
  __shared__ bf16 Vtile[2][64 * 64];
  __shared__ bf16 Pbuf[4][16 * PSTR];
  const int tid = threadIdx.x;
  const int w = tid >> 6, lane = tid & 63;
  const int l16 = lane & 15, quad = lane >> 4;
  const int bh = blockIdx.y, b = bh >> 5, h = bh & 31, kvh = h >> 2;
  bf16* Pw = &Pbuf[w][0];
  const char* Kslice = (const char*)(Kb + ((size_t)(b * NKV + kvh)) * SS * HD);
  const char* Vslice = (const char*)(Vt + ((size_t)(b * NKV + kvh)) * HD * SS);
  const int qrel = w * 16 + l16;

  const int srow = (lane >> 3) & 7;
  const int pchunk = ((lane & 7) ^ srow) << 4;
  const int so = ((quad ^ (l16 & 7)) << 4);
  const int so2 = so ^ 64;

  const int qtA = (int)blockIdx.x;

  int cur = 0;
  {
#pragma unroll
    for (int i = 0; i < 2; ++i) {
      const int r = w * 16 + i * 8 + srow;
      load_lds16(Kslice + (size_t)r * 128 + pchunk,
                 (char*)Ktile[0] + (w * 16 + i * 8) * 128);
      load_lds16(Vslice + (size_t)r * 4096 + pchunk,
                 (char*)Vtile[0] + (w * 16 + i * 8) * 128);
    }
  }

  for (int t = 0; t < 2; ++t) {
    const int qt = t ? (31 - qtA) : qtA;
    const int q = qt * 64 + qrel;

    const bf16* Qp = Qb + ((size_t)(b * SS + q)) * HID + h * HD + quad * 8;
    bf16x8 qb0 = *(const bf16x8*)Qp;
    bf16x8 qb1 = *(const bf16x8*)(Qp + 32);

    float l = 0.f;
    f32x4 oacc[4];
#pragma unroll
    for (int d = 0; d < 4; ++d) oacc[d] = (f32x4){0.f, 0.f, 0.f, 0.f};

    for (int kt = 0; kt <= qt; ++kt) {
      __syncthreads();

      const bool have_next = (kt < qt) || (t == 0);
      if (have_next) {
        const int nkb = (kt < qt) ? (kt + 1) * 64 : 0;
        const int nb = cur ^ 1;
#pragma unroll
        for (int i = 0; i < 2; ++i) {
          const int r = w * 16 + i * 8 + srow;
          load_lds16(Kslice + (size_t)(nkb + r) * 128 + pchunk,
                     (char*)Ktile[nb] + (w * 16 + i * 8) * 128);
          load_lds16(Vslice + (size_t)r * 4096 + (size_t)nkb * 2 + pchunk,
                     (char*)Vtile[nb] + (w * 16 + i * 8) * 128);
        }
      }

      const char* Kc = (const char*)Ktile[cur] + l16 * 128;
      const char* Vc = (const char*)Vtile[cur] + l16 * 128;
      const bool diag = (kt == qt);

#pragma unroll
      for (int nt = 0; nt < 4; ++nt) {
        bf16x8 kf0 = *(const bf16x8*)(Kc + nt * 2048 + so);
        bf16x8 kf1 = *(const bf16x8*)(Kc + nt * 2048 + so2);
        f32x4 s = {0.f, 0.f, 0.f, 0.f};
        s = MFMA16(kf0, qb0, s);
        s = MFMA16(kf1, qb1, s);
        bf16x4 pk;
        if (diag) {
          const int krel = nt * 16 + quad * 4;
#pragma unroll
          for (int r = 0; r < 4; ++r) {
            float p = (krel + r > qrel) ? 0.f : __builtin_amdgcn_exp2f(s[r]);
            l += p;
            pk[r] = (bf16)p;
          }
        } else {
#pragma unroll
          for (int r = 0; r < 4; ++r) {
            float p = __builtin_amdgcn_exp2f(s[r]);
            l += p;
            pk[r] = (bf16)p;
          }
        }
        *(bf16x4*)&Pw[l16 * PSTR + nt * 16 + quad * 4] = pk;
      }

      bf16x8 p0 = *(const bf16x8*)&Pw[l16 * PSTR + quad * 8];
      bf16x8 p1 = *(const bf16x8*)&Pw[l16 * PSTR + 32 + quad * 8];
#pragma unroll
      for (int dn = 0; dn < 4; ++dn) {
        bf16x8 v0 = *(const bf16x8*)(Vc + dn * 2048 + so);
        bf16x8 v1 = *(const bf16x8*)(Vc + dn * 2048 + so2);
        oacc[dn] = MFMA16(v0, p0, oacc[dn]);
        oacc[dn] = MFMA16(v1, p1, oacc[dn]);
      }
      cur ^= 1;
    }

    l += __shfl_xor(l, 16);
    l += __shfl_xor(l, 32);
    const float inv = 1.0f / l;
    bf16* Cp = Ctx + ((size_t)(b * SS + q)) * HID + h * HD + quad * 4;
#pragma unroll
    for (int dn = 0; dn < 4; ++dn) {
      bf16x4 ov;
#pragma unroll
      for (int r = 0; r < 4; ++r) ov[r] = (bf16)(oacc[dn][r] * inv);
      *(bf16x4*)(Cp + dn * 16) = ov;
    }
  }
}

// ---------------- launch ----------------
extern "C" void kernel_launch(void* const* d_in, const int* in_sizes, int n_in,
                              void* d_out, int out_size, void* d_ws, size_t ws_size,
                              hipStream_t stream) {
  const float* hs = (const float*)d_in[0];
  const float* Wq = (const float*)d_in[2];
  const float* Wk = (const float*)d_in[3];
  const float* Wv = (const float*)d_in[4];
  const float* Wo = (const float*)d_in[5];

  char* ws = (char*)d_ws;
  bf16* A_b  = (bf16*)(ws);              // 16 MB ; reused as Ctx after QKV gemm
  bf16* Wq_b = (bf16*)(ws + 16777216);   // 8 MB
  bf16* Wk_b = (bf16*)(ws + 25165824);   // 2 MB
  bf16* Wv_b = (bf16*)(ws + 27262976);   // 2 MB
  bf16* Wo_b = (bf16*)(ws + 29360128);   // 8 MB
  bf16* Qb   = (bf16*)(ws + 37748736);   // 16 MB
  bf16* Kb   = (bf16*)(ws + 54525952);   // 4 MB
  bf16* Vt   = (bf16*)(ws + 58720256);   // 4 MB  (end: 62914560)
  bf16* Ctx  = A_b;

  cvt_all<<<18432, 256, 0, stream>>>(hs, Wq, Wk, Wv, Wo, A_b, Wq_b, Wk_b, Wv_b, Wo_b);
  gemm_qkv<<<dim3(MTOT / 128, 24), 256, 0, stream>>>(A_b, Wq_b, Wk_b, Wv_b, Qb, Kb, Vt);
  attn<<<dim3(16, BB * NH), 256, 0, stream>>>(Qb, Kb, Vt, Ctx);
  gemm_out<<<dim3(MTOT / 128, HID / 128), 256, 0, stream>>>(Ctx, Wo_b, (float*)d_out);
}